// Round 7
// baseline (382.187 us; speedup 1.0000x reference)
//
#include <hip/hip_runtime.h>
#include <hip/hip_fp16.h>
#include <cstdint>
#include <cstddef>

#define NB 4
#define NL 5
#define NC 256
#define NH 96
#define NW 192
#define NHW (NH * NW)
#define NPIX (NB * NHW)   // 73728
#define THRE 0.01f

// ---------------- conf+mask fused: sigmoid/max -> 5x5 gauss -> threshold ----
// tile 32w x 8h, halo +-2. grid = 20 images * 6 * 12 = 1440 blocks.
#define TW 32
#define TH 8
__global__ __launch_bounds__(256) void mask_conv_kernel(const float* __restrict__ rm,
                                                        const float* __restrict__ g,
                                                        float* __restrict__ mask,
                                                        float* __restrict__ counter) {
    const int tilesX = NW / TW;               // 6
    const int tilesY = NH / TH;               // 12
    const int img = blockIdx.x / (tilesX * tilesY);
    const int tidx = blockIdx.x % (tilesX * tilesY);
    const int tx0 = (tidx % tilesX) * TW;
    const int ty0 = (tidx / tilesX) * TH;
    const int t = threadIdx.x;

    __shared__ float cs[TH + 4][TW + 4];

    for (int idx = t; idx < (TH + 4) * (TW + 4); idx += 256) {
        int ly = idx / (TW + 4), lx = idx % (TW + 4);
        int gy = ty0 + ly - 2, gx = tx0 + lx - 2;
        float v = 0.0f;
        if (gy >= 0 && gy < NH && gx >= 0 && gx < NW) {
            float a = rm[((size_t)img * 2 + 0) * NHW + gy * NW + gx];
            float b = rm[((size_t)img * 2 + 1) * NHW + gy * NW + gx];
            v = fmaxf(1.0f / (1.0f + expf(-a)), 1.0f / (1.0f + expf(-b)));
        }
        cs[ly][lx] = v;
    }
    __syncthreads();

    const int lx = t & 31, ly = t >> 5;
    float s = 0.0f;
#pragma unroll
    for (int ky = 0; ky < 5; ky++)
#pragma unroll
        for (int kx = 0; kx < 5; kx++)
            s += cs[ly + ky][lx + kx] * g[ky * 5 + kx];

    float mval = (s > THRE) ? 1.0f : 0.0f;
    mask[(size_t)img * NHW + (ty0 + ly) * NW + tx0 + lx] = mval;

    float cnt = (img % NL == 0) ? mval : 0.0f;
#pragma unroll
    for (int off = 32; off; off >>= 1) cnt += __shfl_down(cnt, off, 64);
    if ((t & 63) == 0 && cnt != 0.0f) atomicAdd(counter, cnt);
}

// ---------------- transpose: x[bm,c,p] fp32 -> xt[bm,p,c] half, mask folded ----
// tile 32 px x 256 ch. LDS as u32 (half2 channel pairs), WPAD=129.
// phase 2: each wave stores 1KB contiguous (2 px x 512B).
#define WPAD 129
__global__ __launch_bounds__(256) void transpose_kernel(const float* __restrict__ x,
                                                        const float* __restrict__ mask,
                                                        __half* __restrict__ xt) {
    const int bm = blockIdx.x / (NHW / 32);
    const int p0 = (blockIdx.x % (NHW / 32)) * 32;
    const int m = bm % NL;
    const int t = threadIdx.x;

    __shared__ unsigned int tile[32 * WPAD];   // 16.5 KB

    const int u = t & 7;        // pixel-quad index (4 px each)
    const int cp = t >> 3;      // channel-pair index 0..31

    float mv[4];
    if (m == 0) {
        mv[0] = mv[1] = mv[2] = mv[3] = 1.0f;
    } else {
#pragma unroll
        for (int j = 0; j < 4; j++)
            mv[j] = mask[(size_t)bm * NHW + p0 + u * 4 + j];
    }

#pragma unroll
    for (int k = 0; k < 4; k++) {
        const int c = cp * 2 + 64 * k;
        float4 f0 = *reinterpret_cast<const float4*>(
            x + ((size_t)bm * NC + c) * NHW + p0 + u * 4);
        float4 f1 = *reinterpret_cast<const float4*>(
            x + ((size_t)bm * NC + c + 1) * NHW + p0 + u * 4);
        const float a0[4] = {f0.x, f0.y, f0.z, f0.w};
        const float a1[4] = {f1.x, f1.y, f1.z, f1.w};
#pragma unroll
        for (int j = 0; j < 4; j++) {
            __half2 h = __halves2half2(__float2half(a0[j] * mv[j]),
                                       __float2half(a1[j] * mv[j]));
            tile[(u * 4 + j) * WPAD + cp + 32 * k] = *reinterpret_cast<unsigned int*>(&h);
        }
    }
    __syncthreads();

    // phase 2: lane = (pw, uu): px pw + j2*8 per iter; uu -> 8 channels
    const int uu = t & 31;      // 32 channel-octets
    const int pw = t >> 5;      // 0..7
#pragma unroll
    for (int j2 = 0; j2 < 4; j2++) {
        const int pl = pw + j2 * 8;
        const unsigned int* src = tile + pl * WPAD + uu * 4;
        uint4 val = make_uint4(src[0], src[1], src[2], src[3]);
        *reinterpret_cast<uint4*>(xt + ((size_t)bm * NHW + p0 + pl) * NC + uu * 8) = val;
    }
}

// ---------------- fused: taps + sample + dots + softmax + out ----------------
// block: 32 consecutive pixels (same image row), 256 thr = 4 waves x 8 px.
// lane owns 4 channels. grid = NB * 576 (XCD-swizzled).
__global__ __launch_bounds__(256) void fused_kernel(const __half* __restrict__ xt,
                                                    const float* __restrict__ M,
                                                    float* __restrict__ out) {
    const int tid = threadIdx.x, wid = tid >> 6, lane = tid & 63;
    const int nblk = NB * (NHW / 32);          // 2304, divisible by 8
    const int bid = (int)((blockIdx.x & 7) * (nblk / 8) + (blockIdx.x >> 3));
    const int b = bid / (NHW / 32);
    const int p0 = (bid % (NHW / 32)) * 32;

    __shared__ float otile[NC][33];

    const float s01 = (float)NH / (float)NW;
    const float s02 = 2.0f / (0.4f * (float)NW);
    const float s10 = (float)NW / (float)NH;
    const float s12 = 2.0f / (0.4f * (float)NH);
    float th[NL][6];
#pragma unroll
    for (int m = 0; m < NL; m++) {
        const float* Mb = M + ((size_t)(b * NL) * NL + m) * 16;
        th[m][0] = Mb[0];
        th[m][1] = Mb[1] * s01;
        th[m][2] = Mb[3] * s02;
        th[m][3] = Mb[4] * s10;
        th[m][4] = Mb[5];
        th[m][5] = Mb[7] * s12;
    }

    const int h = p0 / NW;
    const float gy = (h + 0.5f) * (2.0f / NH) - 1.0f;

#pragma unroll
    for (int i = 0; i < 8; i++) {
        const int pl = wid * 8 + i;
        const int p = p0 + pl;
        const int w = p - h * NW;
        const float gx = (w + 0.5f) * (2.0f / NW) - 1.0f;

        float wt[NL][4]; int off[NL][4];
#pragma unroll
        for (int m = 0; m < NL; m++) {
            float pxn = th[m][0] * gx + th[m][1] * gy + th[m][2];
            float pyn = th[m][3] * gx + th[m][4] * gy + th[m][5];
            float sx = ((pxn + 1.0f) * (float)NW - 1.0f) * 0.5f;
            float sy = ((pyn + 1.0f) * (float)NH - 1.0f) * 0.5f;
            float x0 = floorf(sx), y0 = floorf(sy);
            float fx = sx - x0, fy = sy - y0;
            float xs[2] = {x0, x0 + 1.0f};
            float ys[2] = {y0, y0 + 1.0f};
            float wxv[2] = {1.0f - fx, fx};
            float wyv[2] = {1.0f - fy, fy};
#pragma unroll
            for (int ty = 0; ty < 2; ty++) {
#pragma unroll
                for (int tx = 0; tx < 2; tx++) {
                    int tt = ty * 2 + tx;
                    float xf = xs[tx], yf = ys[ty];
                    bool valid = (xf >= 0.0f) && (xf <= (float)(NW - 1)) &&
                                 (yf >= 0.0f) && (yf <= (float)(NH - 1));
                    int ix = (int)fminf(fmaxf(xf, 0.0f), (float)(NW - 1));
                    int iy = (int)fminf(fmaxf(yf, 0.0f), (float)(NH - 1));
                    off[m][tt] = iy * NW + ix;
                    wt[m][tt] = wxv[tx] * wyv[ty] * (valid ? 1.0f : 0.0f);
                }
            }
        }

        uint2 raw[NL][4];
#pragma unroll
        for (int m = 0; m < NL; m++) {
#pragma unroll
            for (int tt = 0; tt < 4; tt++)
                raw[m][tt] = *reinterpret_cast<const uint2*>(
                    xt + ((size_t)(b * NL + m) * NHW + off[m][tt]) * NC + lane * 4);
        }

        float v[NL][4];
#pragma unroll
        for (int m = 0; m < NL; m++) {
            float acc0 = 0.f, acc1 = 0.f, acc2 = 0.f, acc3 = 0.f;
#pragma unroll
            for (int tt = 0; tt < 4; tt++) {
                const __half2* h2 = reinterpret_cast<const __half2*>(&raw[m][tt]);
                float2 f01 = __half22float2(h2[0]);
                float2 f23 = __half22float2(h2[1]);
                acc0 += wt[m][tt] * f01.x;
                acc1 += wt[m][tt] * f01.y;
                acc2 += wt[m][tt] * f23.x;
                acc3 += wt[m][tt] * f23.y;
            }
            v[m][0] = acc0; v[m][1] = acc1; v[m][2] = acc2; v[m][3] = acc3;
        }

        float dt[NL];
#pragma unroll
        for (int m = 0; m < NL; m++)
            dt[m] = v[0][0] * v[m][0] + v[0][1] * v[m][1] +
                    v[0][2] * v[m][2] + v[0][3] * v[m][3];
#pragma unroll
        for (int m = 0; m < NL; m++) {
#pragma unroll
            for (int msk = 1; msk < 64; msk <<= 1)
                dt[m] += __shfl_xor(dt[m], msk, 64);
        }

        float mx = dt[0] * (1.0f / 16.0f);
#pragma unroll
        for (int m = 1; m < NL; m++) mx = fmaxf(mx, dt[m] * (1.0f / 16.0f));
        float pw[NL], sum = 0.0f;
#pragma unroll
        for (int m = 0; m < NL; m++) {
            pw[m] = expf(dt[m] * (1.0f / 16.0f) - mx);
            sum += pw[m];
        }
        float inv = 1.0f / sum;

#pragma unroll
        for (int j = 0; j < 4; j++) {
            float o = 0.0f;
#pragma unroll
            for (int m = 0; m < NL; m++) o += pw[m] * v[m][j];
            otile[lane * 4 + j][pl] = o * inv;
        }
    }
    __syncthreads();

    const int u = tid & 7;
#pragma unroll
    for (int k = 0; k < 8; k++) {
        const int c = (tid >> 3) + k * 32;
        float4 val = make_float4(otile[c][u * 4 + 0], otile[c][u * 4 + 1],
                                 otile[c][u * 4 + 2], otile[c][u * 4 + 3]);
        *reinterpret_cast<float4*>(out + ((size_t)b * NC + c) * NHW + p0 + u * 4) = val;
    }
}

// ---------------- finalize comm_rate ----------------
__global__ void finalize_kernel(const float* __restrict__ counter, float* __restrict__ out) {
    out[(size_t)NB * NC * NHW] = *counter / (float)(NB * NHW);
}

extern "C" void kernel_launch(void* const* d_in, const int* in_sizes, int n_in,
                              void* d_out, int out_size, void* d_ws, size_t ws_size,
                              hipStream_t stream) {
    const float* x  = (const float*)d_in[0];
    const float* rm = (const float*)d_in[1];
    const float* M  = (const float*)d_in[2];
    const float* g  = (const float*)d_in[3];
    float* out = (float*)d_out;

    float* counter = (float*)d_ws;                        // 16 floats (pad)
    float* mask    = counter + 16;                        // NB*NL*NHW floats
    __half* xt     = (__half*)(mask + (size_t)NB * NL * NHW); // 20*NHW*NC halves

    hipMemsetAsync(counter, 0, sizeof(float), stream);

    mask_conv_kernel<<<NB * NL * (NH / TH) * (NW / TW), 256, 0, stream>>>(rm, g, mask, counter);

    // PROBE (this round only): run the transpose TWICE. The second launch
    // rewrites xt with identical values (idempotent, deterministic), so
    // dur_us(round7) - dur_us(round6) == one transpose_kernel's cost.
    transpose_kernel<<<NB * NL * (NHW / 32), 256, 0, stream>>>(x, mask, xt);
    transpose_kernel<<<NB * NL * (NHW / 32), 256, 0, stream>>>(x, mask, xt);

    fused_kernel<<<NB * (NHW / 32), 256, 0, stream>>>(xt, M, out);
    finalize_kernel<<<1, 1, 0, stream>>>(counter, out);
}

// Round 8
// 262.637 us; speedup vs baseline: 1.4552x; 1.4552x over previous
//
#include <hip/hip_runtime.h>
#include <hip/hip_fp16.h>
#include <cstdint>
#include <cstddef>

#define NB 4
#define NL 5
#define NC 256
#define NH 96
#define NW 192
#define NHW (NH * NW)
#define NPIX (NB * NHW)   // 73728
#define THRE 0.01f

// ---------------- conf+mask fused: sigmoid/max -> 5x5 gauss -> threshold ----
#define TW 32
#define TH 8
__global__ __launch_bounds__(256) void mask_conv_kernel(const float* __restrict__ rm,
                                                        const float* __restrict__ g,
                                                        float* __restrict__ mask,
                                                        float* __restrict__ counter) {
    const int tilesX = NW / TW;               // 6
    const int tilesY = NH / TH;               // 12
    const int img = blockIdx.x / (tilesX * tilesY);
    const int tidx = blockIdx.x % (tilesX * tilesY);
    const int tx0 = (tidx % tilesX) * TW;
    const int ty0 = (tidx / tilesX) * TH;
    const int t = threadIdx.x;

    __shared__ float cs[TH + 4][TW + 4];

    for (int idx = t; idx < (TH + 4) * (TW + 4); idx += 256) {
        int ly = idx / (TW + 4), lx = idx % (TW + 4);
        int gy = ty0 + ly - 2, gx = tx0 + lx - 2;
        float v = 0.0f;
        if (gy >= 0 && gy < NH && gx >= 0 && gx < NW) {
            float a = rm[((size_t)img * 2 + 0) * NHW + gy * NW + gx];
            float b = rm[((size_t)img * 2 + 1) * NHW + gy * NW + gx];
            v = fmaxf(1.0f / (1.0f + expf(-a)), 1.0f / (1.0f + expf(-b)));
        }
        cs[ly][lx] = v;
    }
    __syncthreads();

    const int lx = t & 31, ly = t >> 5;
    float s = 0.0f;
#pragma unroll
    for (int ky = 0; ky < 5; ky++)
#pragma unroll
        for (int kx = 0; kx < 5; kx++)
            s += cs[ly + ky][lx + kx] * g[ky * 5 + kx];

    float mval = (s > THRE) ? 1.0f : 0.0f;
    mask[(size_t)img * NHW + (ty0 + ly) * NW + tx0 + lx] = mval;

    float cnt = (img % NL == 0) ? mval : 0.0f;
#pragma unroll
    for (int off = 32; off; off >>= 1) cnt += __shfl_down(cnt, off, 64);
    if ((t & 63) == 0 && cnt != 0.0f) atomicAdd(counter, cnt);
}

// ---------------- transpose: x[bm,c,p] fp32 -> xt[bm,p,c] half, mask folded ----
#define WPAD 129
__global__ __launch_bounds__(256) void transpose_kernel(const float* __restrict__ x,
                                                        const float* __restrict__ mask,
                                                        __half* __restrict__ xt) {
    const int bm = blockIdx.x / (NHW / 32);
    const int p0 = (blockIdx.x % (NHW / 32)) * 32;
    const int m = bm % NL;
    const int t = threadIdx.x;

    __shared__ unsigned int tile[32 * WPAD];   // 16.5 KB

    const int u = t & 7;        // pixel-quad index (4 px each)
    const int cp = t >> 3;      // channel-pair index 0..31

    float mv[4];
    if (m == 0) {
        mv[0] = mv[1] = mv[2] = mv[3] = 1.0f;
    } else {
#pragma unroll
        for (int j = 0; j < 4; j++)
            mv[j] = mask[(size_t)bm * NHW + p0 + u * 4 + j];
    }

#pragma unroll
    for (int k = 0; k < 4; k++) {
        const int c = cp * 2 + 64 * k;
        float4 f0 = *reinterpret_cast<const float4*>(
            x + ((size_t)bm * NC + c) * NHW + p0 + u * 4);
        float4 f1 = *reinterpret_cast<const float4*>(
            x + ((size_t)bm * NC + c + 1) * NHW + p0 + u * 4);
        const float a0[4] = {f0.x, f0.y, f0.z, f0.w};
        const float a1[4] = {f1.x, f1.y, f1.z, f1.w};
#pragma unroll
        for (int j = 0; j < 4; j++) {
            __half2 h = __halves2half2(__float2half(a0[j] * mv[j]),
                                       __float2half(a1[j] * mv[j]));
            tile[(u * 4 + j) * WPAD + cp + 32 * k] = *reinterpret_cast<unsigned int*>(&h);
        }
    }
    __syncthreads();

    const int uu = t & 31;      // 32 channel-octets
    const int pw = t >> 5;      // 0..7
#pragma unroll
    for (int j2 = 0; j2 < 4; j2++) {
        const int pl = pw + j2 * 8;
        const unsigned int* src = tile + pl * WPAD + uu * 4;
        uint4 val = make_uint4(src[0], src[1], src[2], src[3]);
        *reinterpret_cast<uint4*>(xt + ((size_t)bm * NHW + p0 + pl) * NC + uu * 8) = val;
    }
}

// ---------------- fused: taps + sample + dots + softmax + out ----------------
// block: 32 consecutive pixels (same image row), 256 thr = 4 waves x 8 px.
// lane owns 4 channels. grid = NB * 576 (XCD-swizzled).
// v2: theta coeffs in LDS (-30 VGPR), tap offsets folded into load issue
// (-20 VGPR) -> target <=128 VGPR for 16 waves/CU.
__global__ __launch_bounds__(256) void fused_kernel(const __half* __restrict__ xt,
                                                    const float* __restrict__ M,
                                                    float* __restrict__ out) {
    const int tid = threadIdx.x, wid = tid >> 6, lane = tid & 63;
    const int nblk = NB * (NHW / 32);          // 2304, divisible by 8
    const int bid = (int)((blockIdx.x & 7) * (nblk / 8) + (blockIdx.x >> 3));
    const int b = bid / (NHW / 32);
    const int p0 = (bid % (NHW / 32)) * 32;

    __shared__ float otile[NC][33];
    __shared__ float sh_th[NL][6];

    if (tid < NL) {
        const int m = tid;
        const float* Mb = M + ((size_t)(b * NL) * NL + m) * 16;
        sh_th[m][0] = Mb[0];
        sh_th[m][1] = Mb[1] * ((float)NH / (float)NW);
        sh_th[m][2] = Mb[3] * (2.0f / (0.4f * (float)NW));
        sh_th[m][3] = Mb[4] * ((float)NW / (float)NH);
        sh_th[m][4] = Mb[5];
        sh_th[m][5] = Mb[7] * (2.0f / (0.4f * (float)NH));
    }
    __syncthreads();

    const int h = p0 / NW;
    const float gy = (h + 0.5f) * (2.0f / NH) - 1.0f;

#pragma unroll
    for (int i = 0; i < 8; i++) {
        const int pl = wid * 8 + i;
        const int p = p0 + pl;
        const int w = p - h * NW;
        const float gx = (w + 0.5f) * (2.0f / NW) - 1.0f;

        // per-m: compute taps, issue the 4 loads immediately (addresses die
        // after issue; only wt and raw stay live)
        float wt[NL][4];
        uint2 raw[NL][4];
#pragma unroll
        for (int m = 0; m < NL; m++) {
            float pxn = sh_th[m][0] * gx + sh_th[m][1] * gy + sh_th[m][2];
            float pyn = sh_th[m][3] * gx + sh_th[m][4] * gy + sh_th[m][5];
            float sx = ((pxn + 1.0f) * (float)NW - 1.0f) * 0.5f;
            float sy = ((pyn + 1.0f) * (float)NH - 1.0f) * 0.5f;
            float x0 = floorf(sx), y0 = floorf(sy);
            float fx = sx - x0, fy = sy - y0;
            const __half* base = xt + (size_t)(b * NL + m) * NHW * NC + lane * 4;
#pragma unroll
            for (int ty = 0; ty < 2; ty++) {
#pragma unroll
                for (int tx = 0; tx < 2; tx++) {
                    int tt = ty * 2 + tx;
                    float xf = x0 + (float)tx, yf = y0 + (float)ty;
                    bool valid = (xf >= 0.0f) && (xf <= (float)(NW - 1)) &&
                                 (yf >= 0.0f) && (yf <= (float)(NH - 1));
                    int ix = (int)fminf(fmaxf(xf, 0.0f), (float)(NW - 1));
                    int iy = (int)fminf(fmaxf(yf, 0.0f), (float)(NH - 1));
                    float wx = tx ? fx : (1.0f - fx);
                    float wy = ty ? fy : (1.0f - fy);
                    wt[m][tt] = wx * wy * (valid ? 1.0f : 0.0f);
                    raw[m][tt] = *reinterpret_cast<const uint2*>(
                        base + (size_t)(iy * NW + ix) * NC);
                }
            }
        }

        float v[NL][4];
#pragma unroll
        for (int m = 0; m < NL; m++) {
            float acc0 = 0.f, acc1 = 0.f, acc2 = 0.f, acc3 = 0.f;
#pragma unroll
            for (int tt = 0; tt < 4; tt++) {
                const __half2* h2 = reinterpret_cast<const __half2*>(&raw[m][tt]);
                float2 f01 = __half22float2(h2[0]);
                float2 f23 = __half22float2(h2[1]);
                acc0 += wt[m][tt] * f01.x;
                acc1 += wt[m][tt] * f01.y;
                acc2 += wt[m][tt] * f23.x;
                acc3 += wt[m][tt] * f23.y;
            }
            v[m][0] = acc0; v[m][1] = acc1; v[m][2] = acc2; v[m][3] = acc3;
        }

        float dt[NL];
#pragma unroll
        for (int m = 0; m < NL; m++)
            dt[m] = v[0][0] * v[m][0] + v[0][1] * v[m][1] +
                    v[0][2] * v[m][2] + v[0][3] * v[m][3];
#pragma unroll
        for (int m = 0; m < NL; m++) {
#pragma unroll
            for (int msk = 1; msk < 64; msk <<= 1)
                dt[m] += __shfl_xor(dt[m], msk, 64);
        }

        float mx = dt[0] * (1.0f / 16.0f);
#pragma unroll
        for (int m = 1; m < NL; m++) mx = fmaxf(mx, dt[m] * (1.0f / 16.0f));
        float pw[NL], sum = 0.0f;
#pragma unroll
        for (int m = 0; m < NL; m++) {
            pw[m] = __expf(dt[m] * (1.0f / 16.0f) - mx);
            sum += pw[m];
        }
        float inv = 1.0f / sum;

#pragma unroll
        for (int j = 0; j < 4; j++) {
            float o = 0.0f;
#pragma unroll
            for (int m = 0; m < NL; m++) o += pw[m] * v[m][j];
            otile[lane * 4 + j][pl] = o * inv;
        }
    }
    __syncthreads();

    const int u = tid & 7;
#pragma unroll
    for (int k = 0; k < 8; k++) {
        const int c = (tid >> 3) + k * 32;
        float4 val = make_float4(otile[c][u * 4 + 0], otile[c][u * 4 + 1],
                                 otile[c][u * 4 + 2], otile[c][u * 4 + 3]);
        *reinterpret_cast<float4*>(out + ((size_t)b * NC + c) * NHW + p0 + u * 4) = val;
    }
}

// ---------------- finalize comm_rate ----------------
__global__ void finalize_kernel(const float* __restrict__ counter, float* __restrict__ out) {
    out[(size_t)NB * NC * NHW] = *counter / (float)(NB * NHW);
}

extern "C" void kernel_launch(void* const* d_in, const int* in_sizes, int n_in,
                              void* d_out, int out_size, void* d_ws, size_t ws_size,
                              hipStream_t stream) {
    const float* x  = (const float*)d_in[0];
    const float* rm = (const float*)d_in[1];
    const float* M  = (const float*)d_in[2];
    const float* g  = (const float*)d_in[3];
    float* out = (float*)d_out;

    float* counter = (float*)d_ws;                        // 16 floats (pad)
    float* mask    = counter + 16;                        // NB*NL*NHW floats
    __half* xt     = (__half*)(mask + (size_t)NB * NL * NHW); // 20*NHW*NC halves

    hipMemsetAsync(counter, 0, sizeof(float), stream);

    mask_conv_kernel<<<NB * NL * (NH / TH) * (NW / TW), 256, 0, stream>>>(rm, g, mask, counter);
    transpose_kernel<<<NB * NL * (NHW / 32), 256, 0, stream>>>(x, mask, xt);
    fused_kernel<<<NB * (NHW / 32), 256, 0, stream>>>(xt, M, out);
    finalize_kernel<<<1, 1, 0, stream>>>(counter, out);
}

// Round 9
// 213.235 us; speedup vs baseline: 1.7923x; 1.2317x over previous
//
#include <hip/hip_runtime.h>
#include <hip/hip_fp16.h>
#include <cstdint>
#include <cstddef>

#define NB 4
#define NL 5
#define NC 256
#define NH 96
#define NW 192
#define NHW (NH * NW)
#define NPIX (NB * NHW)   // 73728
#define THRE 0.01f

typedef float __attribute__((ext_vector_type(4))) f32x4;

// ---------------- conf+mask fused: sigmoid/max -> 5x5 gauss -> threshold ----
#define TW 32
#define TH 8
__global__ __launch_bounds__(256) void mask_conv_kernel(const float* __restrict__ rm,
                                                        const float* __restrict__ g,
                                                        float* __restrict__ mask,
                                                        float* __restrict__ counter) {
    const int tilesX = NW / TW;               // 6
    const int tilesY = NH / TH;               // 12
    const int img = blockIdx.x / (tilesX * tilesY);
    const int tidx = blockIdx.x % (tilesX * tilesY);
    const int tx0 = (tidx % tilesX) * TW;
    const int ty0 = (tidx / tilesX) * TH;
    const int t = threadIdx.x;

    __shared__ float cs[TH + 4][TW + 4];

    for (int idx = t; idx < (TH + 4) * (TW + 4); idx += 256) {
        int ly = idx / (TW + 4), lx = idx % (TW + 4);
        int gy = ty0 + ly - 2, gx = tx0 + lx - 2;
        float v = 0.0f;
        if (gy >= 0 && gy < NH && gx >= 0 && gx < NW) {
            float a = rm[((size_t)img * 2 + 0) * NHW + gy * NW + gx];
            float b = rm[((size_t)img * 2 + 1) * NHW + gy * NW + gx];
            v = fmaxf(1.0f / (1.0f + expf(-a)), 1.0f / (1.0f + expf(-b)));
        }
        cs[ly][lx] = v;
    }
    __syncthreads();

    const int lx = t & 31, ly = t >> 5;
    float s = 0.0f;
#pragma unroll
    for (int ky = 0; ky < 5; ky++)
#pragma unroll
        for (int kx = 0; kx < 5; kx++)
            s += cs[ly + ky][lx + kx] * g[ky * 5 + kx];

    float mval = (s > THRE) ? 1.0f : 0.0f;
    mask[(size_t)img * NHW + (ty0 + ly) * NW + tx0 + lx] = mval;

    float cnt = (img % NL == 0) ? mval : 0.0f;
#pragma unroll
    for (int off = 32; off; off >>= 1) cnt += __shfl_down(cnt, off, 64);
    if ((t & 63) == 0 && cnt != 0.0f) atomicAdd(counter, cnt);
}

// ---------------- transpose: x[bm,c,p] fp32 -> xt[bm,p,c] half, mask folded ----
// x loads non-temporal (zero reuse) so they don't evict xt from L3.
#define WPAD 129
__global__ __launch_bounds__(256) void transpose_kernel(const float* __restrict__ x,
                                                        const float* __restrict__ mask,
                                                        __half* __restrict__ xt) {
    const int bm = blockIdx.x / (NHW / 32);
    const int p0 = (blockIdx.x % (NHW / 32)) * 32;
    const int m = bm % NL;
    const int t = threadIdx.x;

    __shared__ unsigned int tile[32 * WPAD];   // 16.5 KB

    const int u = t & 7;        // pixel-quad index (4 px each)
    const int cp = t >> 3;      // channel-pair index 0..31

    float mv[4];
    if (m == 0) {
        mv[0] = mv[1] = mv[2] = mv[3] = 1.0f;
    } else {
#pragma unroll
        for (int j = 0; j < 4; j++)
            mv[j] = mask[(size_t)bm * NHW + p0 + u * 4 + j];
    }

#pragma unroll
    for (int k = 0; k < 4; k++) {
        const int c = cp * 2 + 64 * k;
        f32x4 f0 = __builtin_nontemporal_load(reinterpret_cast<const f32x4*>(
            x + ((size_t)bm * NC + c) * NHW + p0 + u * 4));
        f32x4 f1 = __builtin_nontemporal_load(reinterpret_cast<const f32x4*>(
            x + ((size_t)bm * NC + c + 1) * NHW + p0 + u * 4));
#pragma unroll
        for (int j = 0; j < 4; j++) {
            __half2 h = __halves2half2(__float2half(f0[j] * mv[j]),
                                       __float2half(f1[j] * mv[j]));
            tile[(u * 4 + j) * WPAD + cp + 32 * k] = *reinterpret_cast<unsigned int*>(&h);
        }
    }
    __syncthreads();

    const int uu = t & 31;      // 32 channel-octets
    const int pw = t >> 5;      // 0..7
#pragma unroll
    for (int j2 = 0; j2 < 4; j2++) {
        const int pl = pw + j2 * 8;
        const unsigned int* src = tile + pl * WPAD + uu * 4;
        uint4 val = make_uint4(src[0], src[1], src[2], src[3]);
        *reinterpret_cast<uint4*>(xt + ((size_t)bm * NHW + p0 + pl) * NC + uu * 8) = val;
    }
}

// ---------------- fused v3: 2-deep software-pipelined gather ----------------
// block: 32 consecutive pixels (one image row), 256 thr = 4 waves x 8 px.
// lane owns 4 channels. grid = NB * 576 (XCD-swizzled).
// Pipeline: stage(j+1) (taps + all 20 load issues) placed BEFORE pixel j's
// consumption; double-buffered wt/raw, fully unrolled (static indices).
__global__ __launch_bounds__(256) void fused_kernel(const __half* __restrict__ xt,
                                                    const float* __restrict__ M,
                                                    float* __restrict__ out) {
    const int tid = threadIdx.x, wid = tid >> 6, lane = tid & 63;
    const int nblk = NB * (NHW / 32);          // 2304, divisible by 8
    const int bid = (int)((blockIdx.x & 7) * (nblk / 8) + (blockIdx.x >> 3));
    const int b = bid / (NHW / 32);
    const int p0 = (bid % (NHW / 32)) * 32;

    __shared__ float otile[NC][33];
    __shared__ float sh_th[NL][6];

    if (tid < NL) {
        const int m = tid;
        const float* Mb = M + ((size_t)(b * NL) * NL + m) * 16;
        sh_th[m][0] = Mb[0];
        sh_th[m][1] = Mb[1] * ((float)NH / (float)NW);
        sh_th[m][2] = Mb[3] * (2.0f / (0.4f * (float)NW));
        sh_th[m][3] = Mb[4] * ((float)NW / (float)NH);
        sh_th[m][4] = Mb[5];
        sh_th[m][5] = Mb[7] * (2.0f / (0.4f * (float)NH));
    }
    __syncthreads();

    const int h = p0 / NW;
    const int w0 = p0 - h * NW;
    const float gy = (h + 0.5f) * (2.0f / NH) - 1.0f;

    float wt[2][NL][4];
    uint2 raw[2][NL][4];

    // taps + load issue for pixel slot j into buffer buf
    auto stage = [&](int j, int buf) {
        const int pl = wid * 8 + j;
        const float gx = (w0 + pl + 0.5f) * (2.0f / NW) - 1.0f;
#pragma unroll
        for (int m = 0; m < NL; m++) {
            float pxn = sh_th[m][0] * gx + sh_th[m][1] * gy + sh_th[m][2];
            float pyn = sh_th[m][3] * gx + sh_th[m][4] * gy + sh_th[m][5];
            float sx = ((pxn + 1.0f) * (float)NW - 1.0f) * 0.5f;
            float sy = ((pyn + 1.0f) * (float)NH - 1.0f) * 0.5f;
            float x0 = floorf(sx), y0 = floorf(sy);
            float fx = sx - x0, fy = sy - y0;
            const __half* base = xt + (size_t)(b * NL + m) * NHW * NC + lane * 4;
#pragma unroll
            for (int ty = 0; ty < 2; ty++) {
#pragma unroll
                for (int tx = 0; tx < 2; tx++) {
                    int tt = ty * 2 + tx;
                    float xf = x0 + (float)tx, yf = y0 + (float)ty;
                    bool valid = (xf >= 0.0f) && (xf <= (float)(NW - 1)) &&
                                 (yf >= 0.0f) && (yf <= (float)(NH - 1));
                    int ix = (int)fminf(fmaxf(xf, 0.0f), (float)(NW - 1));
                    int iy = (int)fminf(fmaxf(yf, 0.0f), (float)(NH - 1));
                    float wx = tx ? fx : (1.0f - fx);
                    float wy = ty ? fy : (1.0f - fy);
                    wt[buf][m][tt] = wx * wy * (valid ? 1.0f : 0.0f);
                    raw[buf][m][tt] = *reinterpret_cast<const uint2*>(
                        base + (size_t)(iy * NW + ix) * NC);
                }
            }
        }
    };

    stage(0, 0);

#pragma unroll
    for (int j = 0; j < 8; j++) {
        const int cur = j & 1;
        if (j < 7) stage(j + 1, cur ^ 1);   // next pixel's loads in flight

        const int pl = wid * 8 + j;

        float v[NL][4];
#pragma unroll
        for (int m = 0; m < NL; m++) {
            float acc0 = 0.f, acc1 = 0.f, acc2 = 0.f, acc3 = 0.f;
#pragma unroll
            for (int tt = 0; tt < 4; tt++) {
                const __half2* h2 = reinterpret_cast<const __half2*>(&raw[cur][m][tt]);
                float2 f01 = __half22float2(h2[0]);
                float2 f23 = __half22float2(h2[1]);
                float wv = wt[cur][m][tt];
                acc0 += wv * f01.x;
                acc1 += wv * f01.y;
                acc2 += wv * f23.x;
                acc3 += wv * f23.y;
            }
            v[m][0] = acc0; v[m][1] = acc1; v[m][2] = acc2; v[m][3] = acc3;
        }

        float dt[NL];
#pragma unroll
        for (int m = 0; m < NL; m++)
            dt[m] = v[0][0] * v[m][0] + v[0][1] * v[m][1] +
                    v[0][2] * v[m][2] + v[0][3] * v[m][3];
#pragma unroll
        for (int m = 0; m < NL; m++) {
#pragma unroll
            for (int msk = 1; msk < 64; msk <<= 1)
                dt[m] += __shfl_xor(dt[m], msk, 64);
        }

        float mx = dt[0] * (1.0f / 16.0f);
#pragma unroll
        for (int m = 1; m < NL; m++) mx = fmaxf(mx, dt[m] * (1.0f / 16.0f));
        float pw[NL], sum = 0.0f;
#pragma unroll
        for (int m = 0; m < NL; m++) {
            pw[m] = __expf(dt[m] * (1.0f / 16.0f) - mx);
            sum += pw[m];
        }
        float inv = 1.0f / sum;

#pragma unroll
        for (int jj = 0; jj < 4; jj++) {
            float o = 0.0f;
#pragma unroll
            for (int m = 0; m < NL; m++) o += pw[m] * v[m][jj];
            otile[lane * 4 + jj][pl] = o * inv;
        }
    }
    __syncthreads();

    const int u = tid & 7;
#pragma unroll
    for (int k = 0; k < 8; k++) {
        const int c = (tid >> 3) + k * 32;
        float4 val = make_float4(otile[c][u * 4 + 0], otile[c][u * 4 + 1],
                                 otile[c][u * 4 + 2], otile[c][u * 4 + 3]);
        *reinterpret_cast<float4*>(out + ((size_t)b * NC + c) * NHW + p0 + u * 4) = val;
    }
}

// ---------------- finalize comm_rate ----------------
__global__ void finalize_kernel(const float* __restrict__ counter, float* __restrict__ out) {
    out[(size_t)NB * NC * NHW] = *counter / (float)(NB * NHW);
}

extern "C" void kernel_launch(void* const* d_in, const int* in_sizes, int n_in,
                              void* d_out, int out_size, void* d_ws, size_t ws_size,
                              hipStream_t stream) {
    const float* x  = (const float*)d_in[0];
    const float* rm = (const float*)d_in[1];
    const float* M  = (const float*)d_in[2];
    const float* g  = (const float*)d_in[3];
    float* out = (float*)d_out;

    float* counter = (float*)d_ws;                        // 16 floats (pad)
    float* mask    = counter + 16;                        // NB*NL*NHW floats
    __half* xt     = (__half*)(mask + (size_t)NB * NL * NHW); // 20*NHW*NC halves

    hipMemsetAsync(counter, 0, sizeof(float), stream);

    mask_conv_kernel<<<NB * NL * (NH / TH) * (NW / TW), 256, 0, stream>>>(rm, g, mask, counter);
    transpose_kernel<<<NB * NL * (NHW / 32), 256, 0, stream>>>(x, mask, xt);
    fused_kernel<<<NB * (NHW / 32), 256, 0, stream>>>(xt, M, out);
    finalize_kernel<<<1, 1, 0, stream>>>(counter, out);
}